// Round 3
// baseline (228.186 us; speedup 1.0000x reference)
//
#include <hip/hip_runtime.h>
#include <hip/hip_cooperative_groups.h>

namespace cg = cooperative_groups;

// MPS VQE, fully fused single cooperative kernel.
// H symmetric (bitwise 0.5*(A+A^T)) =>
//   (1) <psi|H^2|psi> = ||H psi||^2  -> only ONE matvec needed
//   (2) SYMV tiling: read only upper-triangular 128x128 tiles (528/1024)
//       -> matvec HBM traffic ~34.6 MB (floor 33.6 MB).
// Phases: [build psi per-tile in-block] -> grid.sync ->
//         [symv tiles, atomic scatter]  -> grid.sync ->
//         [block 0: three double dots + finalize]

#define DIM 4096
#define BOND 8
#define NMID 10
#define T 128
#define NT (DIM / T)                 // 32
#define NPAIRS (NT * (NT + 1) / 2)   // 528

__global__ __launch_bounds__(256, 3) void fused_vqe_kernel(
    const float* __restrict__ core0,      // (2, 8)
    const float* __restrict__ cores_mid,  // (10, 8, 2, 8)
    const float* __restrict__ core_last,  // (8, 2)
    const float* __restrict__ H,          // (4096, 4096) symmetric
    float* __restrict__ psi_g,            // ws
    float* __restrict__ hpsi_g,           // ws
    float* __restrict__ out) {
  cg::grid_group grid = cg::this_grid();

  __shared__ float c0[16], cm[NMID * 128], cl[16];
  __shared__ float xI[T], xJ[T], yI_s[T], yJp[4 * T];
  __shared__ double sred[12];

  // triangular linear index -> (bi, bj), bi <= bj
  int rem = blockIdx.x;
  int bi = 0;
  while (rem >= NT - bi) { rem -= (NT - bi); ++bi; }
  const int bj = bi + rem;
  const bool diag = (bi == bj);

  // ---- stage cores in LDS ----
  if (threadIdx.x < 16) {
    c0[threadIdx.x] = core0[threadIdx.x];
    cl[threadIdx.x] = core_last[threadIdx.x];
  }
  for (int j = threadIdx.x; j < NMID * 128; j += 256) cm[j] = cores_mid[j];
  __syncthreads();

  // ---- phase 0: build this block's psi slices (xI, xJ) ----
  {
    const int local = threadIdx.x & 127;
    const int slice = (threadIdx.x < 128) ? bi : bj;
    const int idx = slice * T + local;

    float v[BOND], nv[BOND];
    const int s0 = (idx >> 11) & 1;
#pragma unroll
    for (int a = 0; a < BOND; a++) v[a] = c0[s0 * BOND + a];
#pragma unroll
    for (int i = 0; i < NMID; i++) {
      const int p = (idx >> (10 - i)) & 1;
      const float* M = &cm[i * 128 + p * BOND];  // M[a][b] at M[a*16 + b]
#pragma unroll
      for (int b = 0; b < BOND; b++) nv[b] = v[0] * M[b];
#pragma unroll
      for (int a = 1; a < BOND; a++) {
#pragma unroll
        for (int b = 0; b < BOND; b++) nv[b] += v[a] * M[a * 16 + b];
      }
#pragma unroll
      for (int a = 0; a < BOND; a++) v[a] = nv[a];
    }
    const int pl = idx & 1;
    float ps = 0.f;
#pragma unroll
    for (int a = 0; a < BOND; a++) ps += v[a] * cl[a * 2 + pl];

    if (threadIdx.x < 128) xI[local] = ps; else xJ[local] = ps;

    // diag blocks publish psi + zero hpsi (32 blocks cover all 4096 elems, disjoint)
    if (diag && threadIdx.x < 128) {
      psi_g[idx] = ps;
      hpsi_g[idx] = 0.f;
    }
  }
  __syncthreads();
  grid.sync();  // hpsi zeroed, psi published

  // ---- phase 1: symv on tile (bi, bj) ----
  const int wave = threadIdx.x >> 6;
  const int lane = threadIdx.x & 63;
  const float* __restrict__ base = H + (size_t)(bi * T) * DIM + bj * T;

  float aJx = 0.f, aJy = 0.f;
  const float pJx = xJ[lane * 2], pJy = xJ[lane * 2 + 1];

#pragma unroll 4
  for (int k = 0; k < T / 4; ++k) {
    const int r = k * 4 + wave;  // rows partitioned across the 4 waves
    const float2 a = *reinterpret_cast<const float2*>(base + (size_t)r * DIM + lane * 2);
    const float xr = xI[r];
    aJx += a.x * xr;
    aJy += a.y * xr;
    float d = a.x * pJx + a.y * pJy;
#pragma unroll
    for (int off = 32; off > 0; off >>= 1) d += __shfl_down(d, off, 64);
    if (lane == 0) yI_s[r] = d;
  }

  yJp[wave * T + lane * 2] = aJx;
  yJp[wave * T + lane * 2 + 1] = aJy;
  __syncthreads();

  if (threadIdx.x < T) {
    atomicAdd(&hpsi_g[bi * T + threadIdx.x], yI_s[threadIdx.x]);
    if (!diag) {
      const float yj = yJp[threadIdx.x] + yJp[T + threadIdx.x] +
                       yJp[2 * T + threadIdx.x] + yJp[3 * T + threadIdx.x];
      atomicAdd(&hpsi_g[bj * T + threadIdx.x], yj);
    }
  }
  grid.sync();  // hpsi complete

  // ---- phase 2: block 0 computes the three dots + finalizes ----
  if (blockIdx.x == 0) {
    double n = 0.0, ph = 0.0, hh = 0.0;
    for (int i = threadIdx.x; i < DIM; i += 256) {
      const double p = (double)psi_g[i];
      const double h = (double)hpsi_g[i];
      n += p * p;
      ph += p * h;
      hh += h * h;
    }
#pragma unroll
    for (int off = 32; off > 0; off >>= 1) {
      n += __shfl_down(n, off, 64);
      ph += __shfl_down(ph, off, 64);
      hh += __shfl_down(hh, off, 64);
    }
    if (lane == 0) { sred[wave] = n; sred[4 + wave] = ph; sred[8 + wave] = hh; }
    __syncthreads();
    if (threadIdx.x == 0) {
      double N = 0.0, P = 0.0, HH = 0.0;
#pragma unroll
      for (int w = 0; w < 4; w++) { N += sred[w]; P += sred[4 + w]; HH += sred[8 + w]; }
      const double e = P / N;
      const double e2 = HH / N;
      double var = e2 - e * e;
      if (var < 0.0) var = 0.0;
      out[0] = (float)e;
      out[1] = (float)var;
    }
  }
}

extern "C" void kernel_launch(void* const* d_in, const int* in_sizes, int n_in,
                              void* d_out, int out_size, void* d_ws, size_t ws_size,
                              hipStream_t stream) {
  const float* core0 = (const float*)d_in[0];
  const float* cores_mid = (const float*)d_in[1];
  const float* core_last = (const float*)d_in[2];
  const float* H = (const float*)d_in[3];

  float* psi = (float*)d_ws;
  float* hpsi = psi + DIM;
  float* out = (float*)d_out;

  void* args[] = {(void*)&core0, (void*)&cores_mid, (void*)&core_last,
                  (void*)&H, (void*)&psi, (void*)&hpsi, (void*)&out};
  hipLaunchCooperativeKernel((const void*)fused_vqe_kernel, dim3(NPAIRS),
                             dim3(256), args, 0, stream);
}

// Round 4
// 132.596 us; speedup vs baseline: 1.7209x; 1.7209x over previous
//
#include <hip/hip_runtime.h>
#include <hip/hip_bf16.h>

// MPS VQE, 2-dispatch design (grid.sync proved ~60us/sync in R3 -> removed).
// H symmetric (bitwise 0.5*(A+A^T)) =>
//   (1) <psi|H^2|psi> = ||H psi||^2  -> only ONE matvec needed
//   (2) SYMV tiling: read only upper-triangular 128x128 tiles (528/1024).
// Dispatch 1: zero hpsi + completion counter (tiny).
// Dispatch 2: per tile-block: build psi slices in-registers -> symv tile ->
//             atomic scatter -> last-finishing block (atomic counter) does the
//             three double-precision dots + finalize. No grid-wide barrier.

#define DIM 4096
#define BOND 8
#define NMID 10
#define T 128
#define NT (DIM / T)                 // 32
#define NPAIRS (NT * (NT + 1) / 2)   // 528

// ws layout: psi[4096] f32, hpsi[4096] f32, cnt (int)

// ---------------- Kernel 1: init ----------------
__global__ __launch_bounds__(256) void init_kernel(float* __restrict__ hpsi_g,
                                                   int* __restrict__ cnt) {
  const float4 z = {0.f, 0.f, 0.f, 0.f};
  reinterpret_cast<float4*>(hpsi_g)[blockIdx.x * 256 + threadIdx.x] = z;
  if (blockIdx.x == 0 && threadIdx.x == 0) *cnt = 0;
}

// ---------------- Kernel 2: fused build + symv + last-block dots ----------
__global__ __launch_bounds__(256) void fused_kernel(
    const float* __restrict__ core0,      // (2, 8)
    const float* __restrict__ cores_mid,  // (10, 8, 2, 8)
    const float* __restrict__ core_last,  // (8, 2)
    const float* __restrict__ H,          // (4096, 4096) symmetric
    float* __restrict__ psi_g,
    float* __restrict__ hpsi_g,
    int* __restrict__ cnt,
    float* __restrict__ out) {
  __shared__ float c0[16], cm[NMID * 128], cl[16];
  __shared__ float xI[T], xJ[T], yI_s[T], yJp[4 * T];
  __shared__ double sred[12];
  __shared__ int s_old;

  // triangular linear index -> (bi, bj), bi <= bj
  int rem = blockIdx.x;
  int bi = 0;
  while (rem >= NT - bi) { rem -= (NT - bi); ++bi; }
  const int bj = bi + rem;
  const bool diag = (bi == bj);

  // ---- stage cores in LDS ----
  if (threadIdx.x < 16) {
    c0[threadIdx.x] = core0[threadIdx.x];
    cl[threadIdx.x] = core_last[threadIdx.x];
  }
  for (int j = threadIdx.x; j < NMID * 128; j += 256) cm[j] = cores_mid[j];
  __syncthreads();

  // ---- phase 0: build this block's psi slices (xI, xJ) ----
  {
    const int local = threadIdx.x & 127;
    const int slice = (threadIdx.x < 128) ? bi : bj;
    const int idx = slice * T + local;

    float v[BOND], nv[BOND];
    const int s0 = (idx >> 11) & 1;
#pragma unroll
    for (int a = 0; a < BOND; a++) v[a] = c0[s0 * BOND + a];
#pragma unroll
    for (int i = 0; i < NMID; i++) {
      const int p = (idx >> (10 - i)) & 1;
      const float* M = &cm[i * 128 + p * BOND];  // M[a][b] at M[a*16 + b]
#pragma unroll
      for (int b = 0; b < BOND; b++) nv[b] = v[0] * M[b];
#pragma unroll
      for (int a = 1; a < BOND; a++) {
#pragma unroll
        for (int b = 0; b < BOND; b++) nv[b] += v[a] * M[a * 16 + b];
      }
#pragma unroll
      for (int a = 0; a < BOND; a++) v[a] = nv[a];
    }
    const int pl = idx & 1;
    float ps = 0.f;
#pragma unroll
    for (int a = 0; a < BOND; a++) ps += v[a] * cl[a * 2 + pl];

    if (threadIdx.x < 128) xI[local] = ps; else xJ[local] = ps;

    // diag blocks publish psi (32 diag blocks cover all 4096 elems, disjoint)
    if (diag && threadIdx.x < 128) psi_g[idx] = ps;
  }
  __syncthreads();

  // ---- phase 1: symv on tile (bi, bj) (R2-verified structure) ----
  const int wave = threadIdx.x >> 6;
  const int lane = threadIdx.x & 63;
  const float* __restrict__ base = H + (size_t)(bi * T) * DIM + bj * T;

  float aJx = 0.f, aJy = 0.f;
  const float pJx = xJ[lane * 2], pJy = xJ[lane * 2 + 1];

#pragma unroll 4
  for (int k = 0; k < T / 4; ++k) {
    const int r = k * 4 + wave;  // rows partitioned across the 4 waves
    const float2 a = *reinterpret_cast<const float2*>(base + (size_t)r * DIM + lane * 2);
    const float xr = xI[r];
    aJx += a.x * xr;
    aJy += a.y * xr;
    float d = a.x * pJx + a.y * pJy;
#pragma unroll
    for (int off = 32; off > 0; off >>= 1) d += __shfl_down(d, off, 64);
    if (lane == 0) yI_s[r] = d;
  }

  yJp[wave * T + lane * 2] = aJx;
  yJp[wave * T + lane * 2 + 1] = aJy;
  __syncthreads();

  if (threadIdx.x < T) {
    atomicAdd(&hpsi_g[bi * T + threadIdx.x], yI_s[threadIdx.x]);
    if (!diag) {
      const float yj = yJp[threadIdx.x] + yJp[T + threadIdx.x] +
                       yJp[2 * T + threadIdx.x] + yJp[3 * T + threadIdx.x];
      atomicAdd(&hpsi_g[bj * T + threadIdx.x], yj);
    }
  }
  __syncthreads();  // all this block's atomics issued & complete

  // ---- phase 2: last-finishing block does dots + finalize ----
  if (threadIdx.x == 0) {
    __threadfence();                 // release psi stores + order before count
    s_old = atomicAdd(cnt, 1);
  }
  __syncthreads();
  if (s_old == NPAIRS - 1) {
    __threadfence();                 // acquire
    double n = 0.0, ph = 0.0, hh = 0.0;
    for (int i = threadIdx.x; i < DIM; i += 256) {
      const float p = __hip_atomic_load(&psi_g[i], __ATOMIC_RELAXED,
                                        __HIP_MEMORY_SCOPE_AGENT);
      const float h = __hip_atomic_load(&hpsi_g[i], __ATOMIC_RELAXED,
                                        __HIP_MEMORY_SCOPE_AGENT);
      const double pd = (double)p, hd = (double)h;
      n += pd * pd;
      ph += pd * hd;
      hh += hd * hd;
    }
#pragma unroll
    for (int off = 32; off > 0; off >>= 1) {
      n += __shfl_down(n, off, 64);
      ph += __shfl_down(ph, off, 64);
      hh += __shfl_down(hh, off, 64);
    }
    if (lane == 0) { sred[wave] = n; sred[4 + wave] = ph; sred[8 + wave] = hh; }
    __syncthreads();
    if (threadIdx.x == 0) {
      double N = 0.0, P = 0.0, HH = 0.0;
#pragma unroll
      for (int w = 0; w < 4; w++) { N += sred[w]; P += sred[4 + w]; HH += sred[8 + w]; }
      const double e = P / N;
      const double e2 = HH / N;
      double var = e2 - e * e;
      if (var < 0.0) var = 0.0;
      out[0] = (float)e;
      out[1] = (float)var;
    }
  }
}

extern "C" void kernel_launch(void* const* d_in, const int* in_sizes, int n_in,
                              void* d_out, int out_size, void* d_ws, size_t ws_size,
                              hipStream_t stream) {
  const float* core0 = (const float*)d_in[0];
  const float* cores_mid = (const float*)d_in[1];
  const float* core_last = (const float*)d_in[2];
  const float* H = (const float*)d_in[3];

  float* psi = (float*)d_ws;
  float* hpsi = psi + DIM;
  int* cnt = (int*)(hpsi + DIM);

  init_kernel<<<4, 256, 0, stream>>>(hpsi, cnt);
  fused_kernel<<<NPAIRS, 256, 0, stream>>>(core0, cores_mid, core_last, H,
                                           psi, hpsi, cnt, (float*)d_out);
}

// Round 5
// 124.666 us; speedup vs baseline: 1.8304x; 1.0636x over previous
//
#include <hip/hip_runtime.h>
#include <hip/hip_bf16.h>

// MPS VQE, 2-dispatch design.
// H symmetric (bitwise 0.5*(A+A^T)) =>
//   (1) <psi|H^2|psi> = ||H psi||^2  -> only ONE matvec needed
//   (2) SYMV tiling: read only upper-triangular 128x128 tiles (528/1024).
// R4 lesson: symv must have NO dependent cross-lane ops in the K-loop and
// psi must be built once, not per-tile-block.
// Dispatch 1 (16 blocks): build psi, zero hpsi, zero counter.
// Dispatch 2 (528 blocks): tile symv with deferred reductions; the
// last-finishing block (atomic counter) does the three double dots + finalize.

#define DIM 4096
#define BOND 8
#define NMID 10
#define T 128
#define NT (DIM / T)                 // 32
#define NPAIRS (NT * (NT + 1) / 2)   // 528

// ws layout: psi[4096] f32, hpsi[4096] f32, cnt (int)

// ---------------- Kernel 1: build psi + zero hpsi + zero cnt ----------------
__global__ __launch_bounds__(256) void init_kernel(
    const float* __restrict__ core0,      // (2, 8)
    const float* __restrict__ cores_mid,  // (10, 8, 2, 8)
    const float* __restrict__ core_last,  // (8, 2)
    float* __restrict__ psi_g,
    float* __restrict__ hpsi_g,
    int* __restrict__ cnt) {
  __shared__ float c0[16], cm[NMID * 128], cl[16];

  if (threadIdx.x < 16) {
    c0[threadIdx.x] = core0[threadIdx.x];
    cl[threadIdx.x] = core_last[threadIdx.x];
  }
  for (int j = threadIdx.x; j < NMID * 128; j += 256) cm[j] = cores_mid[j];
  __syncthreads();

  const int idx = blockIdx.x * 256 + threadIdx.x;  // 0..4095
  hpsi_g[idx] = 0.f;
  if (idx == 0) *cnt = 0;

  float v[BOND], nv[BOND];
  const int s0 = (idx >> 11) & 1;
#pragma unroll
  for (int a = 0; a < BOND; a++) v[a] = c0[s0 * BOND + a];
#pragma unroll
  for (int i = 0; i < NMID; i++) {
    const int p = (idx >> (10 - i)) & 1;
    const float* M = &cm[i * 128 + p * BOND];  // M[a][b] at M[a*16 + b]
#pragma unroll
    for (int b = 0; b < BOND; b++) nv[b] = v[0] * M[b];
#pragma unroll
    for (int a = 1; a < BOND; a++) {
#pragma unroll
      for (int b = 0; b < BOND; b++) nv[b] += v[a] * M[a * 16 + b];
    }
#pragma unroll
    for (int a = 0; a < BOND; a++) v[a] = nv[a];
  }
  const int pl = idx & 1;
  float ps = 0.f;
#pragma unroll
  for (int a = 0; a < BOND; a++) ps += v[a] * cl[a * 2 + pl];
  psi_g[idx] = ps;
}

// ---------------- Kernel 2: symv tiles + last-block dots ----------------
__global__ __launch_bounds__(256) void symv_kernel(
    const float* __restrict__ H,
    const float* __restrict__ psi_g,
    float* __restrict__ hpsi_g,
    int* __restrict__ cnt,
    float* __restrict__ out) {
  __shared__ float xI[T], xJ[T];
  __shared__ float yIp[32 * 129];  // [l31][row], stride 129 -> conflict-free
  __shared__ float yJp[8 * 128];   // [wave*2+half][col]
  __shared__ double sred[12];
  __shared__ int s_old;

  // triangular linear index -> (bi, bj), bi <= bj
  int rem = blockIdx.x;
  int bi = 0;
  while (rem >= NT - bi) { rem -= (NT - bi); ++bi; }
  const int bj = bi + rem;
  const bool diag = (bi == bj);

  if (threadIdx.x < T) xI[threadIdx.x] = psi_g[bi * T + threadIdx.x];
  else xJ[threadIdx.x - T] = psi_g[bj * T + threadIdx.x - T];
  __syncthreads();

  const int wave = threadIdx.x >> 6;
  const int lane = threadIdx.x & 63;
  const int half = lane >> 5;
  const int l31 = lane & 31;
  const int c = l31 * 4;  // column base (float4 per lane, 32 lanes cover 128)

  const float4 pj = *reinterpret_cast<const float4*>(&xJ[c]);  // loop-invariant
  const float* __restrict__ base = H + (size_t)(bi * T) * DIM + bj * T;

  // K-loop: 16 independent float4 loads per wave; NO cross-lane ops inside.
  float4 aJ = {0.f, 0.f, 0.f, 0.f};
#pragma unroll
  for (int k = 0; k < 16; ++k) {
    const int r = k * 8 + wave * 2 + half;  // rows; 2 rows per wave-iter
    const float4 a = *reinterpret_cast<const float4*>(base + (size_t)r * DIM + c);
    const float xr = xI[r];
    aJ.x += a.x * xr; aJ.y += a.y * xr; aJ.z += a.z * xr; aJ.w += a.w * xr;
    yIp[l31 * 129 + r] = a.x * pj.x + a.y * pj.y + a.z * pj.z + a.w * pj.w;
  }
  *reinterpret_cast<float4*>(&yJp[(wave * 2 + half) * 128 + c]) = aJ;
  __syncthreads();

  // deferred reduce: yI (row dots) — 2 threads/row, 16 LDS reads each
  {
    const int r = threadIdx.x >> 1;
    const int h = threadIdx.x & 1;
    float s = 0.f;
#pragma unroll
    for (int i = 0; i < 16; ++i) s += yIp[(16 * h + i) * 129 + r];
    s += __shfl_down(s, 1, 64);
    if (h == 0) atomicAdd(&hpsi_g[bi * T + r], s);
  }
  // deferred reduce: yJ (transpose) — skip on diagonal tiles
  if (!diag && threadIdx.x < T) {
    float s = 0.f;
#pragma unroll
    for (int q = 0; q < 8; ++q) s += yJp[q * 128 + threadIdx.x];
    atomicAdd(&hpsi_g[bj * T + threadIdx.x], s);
  }
  __syncthreads();

  // last-finishing block computes the three dots + finalizes (R4-verified)
  if (threadIdx.x == 0) {
    __threadfence();
    s_old = atomicAdd(cnt, 1);
  }
  __syncthreads();
  if (s_old == NPAIRS - 1) {
    __threadfence();
    double n = 0.0, ph = 0.0, hh = 0.0;
    for (int i = threadIdx.x; i < DIM; i += 256) {
      const float p = __hip_atomic_load(&psi_g[i], __ATOMIC_RELAXED,
                                        __HIP_MEMORY_SCOPE_AGENT);
      const float h = __hip_atomic_load(&hpsi_g[i], __ATOMIC_RELAXED,
                                        __HIP_MEMORY_SCOPE_AGENT);
      const double pd = (double)p, hd = (double)h;
      n += pd * pd;
      ph += pd * hd;
      hh += hd * hd;
    }
#pragma unroll
    for (int off = 32; off > 0; off >>= 1) {
      n += __shfl_down(n, off, 64);
      ph += __shfl_down(ph, off, 64);
      hh += __shfl_down(hh, off, 64);
    }
    if (lane == 0) { sred[wave] = n; sred[4 + wave] = ph; sred[8 + wave] = hh; }
    __syncthreads();
    if (threadIdx.x == 0) {
      double N = 0.0, P = 0.0, HH = 0.0;
#pragma unroll
      for (int w = 0; w < 4; w++) { N += sred[w]; P += sred[4 + w]; HH += sred[8 + w]; }
      const double e = P / N;
      const double e2 = HH / N;
      double var = e2 - e * e;
      if (var < 0.0) var = 0.0;
      out[0] = (float)e;
      out[1] = (float)var;
    }
  }
}

extern "C" void kernel_launch(void* const* d_in, const int* in_sizes, int n_in,
                              void* d_out, int out_size, void* d_ws, size_t ws_size,
                              hipStream_t stream) {
  const float* core0 = (const float*)d_in[0];
  const float* cores_mid = (const float*)d_in[1];
  const float* core_last = (const float*)d_in[2];
  const float* H = (const float*)d_in[3];

  float* psi = (float*)d_ws;
  float* hpsi = psi + DIM;
  int* cnt = (int*)(hpsi + DIM);

  init_kernel<<<DIM / 256, 256, 0, stream>>>(core0, cores_mid, core_last, psi, hpsi, cnt);
  symv_kernel<<<NPAIRS, 256, 0, stream>>>(H, psi, hpsi, cnt, (float*)d_out);
}